// Round 3
// baseline (1007.189 us; speedup 1.0000x reference)
//
#include <hip/hip_runtime.h>
#include <hip/hip_fp16.h>
#include <cstdint>
#include <cstddef>

typedef unsigned short u16t;
typedef __bf16 bf16x8 __attribute__((ext_vector_type(8)));
typedef float f32x4 __attribute__((ext_vector_type(4)));
typedef unsigned short u16x8 __attribute__((ext_vector_type(8)));

#define BT_ROWS 51200   // B*T
#define MODEL 512
#define FFNH 2048

__device__ __forceinline__ float bf2f(u16t u) {
  union { unsigned int i; float f; } v; v.i = ((unsigned int)u) << 16; return v.f;
}
__device__ __forceinline__ u16t f2bf(float f) {
  union { float f; unsigned int i; } v; v.f = f;
  return (u16t)((v.i + 0x7fffu + ((v.i >> 16) & 1u)) >> 16);
}
// dt: 0 = bf16, 1 = fp32, 2 = fp16
__device__ __forceinline__ float ldf(const void* p, size_t i, int dt) {
  if (dt == 1) return ((const float*)p)[i];
  u16t u = ((const u16t*)p)[i];
  if (dt == 0) return bf2f(u);
  __half h; *(u16t*)&h = u; return __half2float(h);
}
__device__ __forceinline__ void stf(void* p, size_t i, int dt, float f) {
  if (dt == 1) { ((float*)p)[i] = f; }
  else if (dt == 0) { ((u16t*)p)[i] = f2bf(f); }
  else { __half h = __float2half(f); ((u16t*)p)[i] = *(u16t*)&h; }
}
__device__ __forceinline__ void gl2lds16(const void* g, void* l) {
  __builtin_amdgcn_global_load_lds((const __attribute__((address_space(1))) void*)g,
                                   (__attribute__((address_space(3))) void*)l, 16, 0, 0);
}

// ---------------- dtype probe on w1 (Xavier: |x| < 0.0485 in its own dtype) ----------------
__global__ __launch_bounds__(256) void detect_dtype_k(const unsigned int* __restrict__ w1,
                                                      int* __restrict__ cnts) {
  int i = blockIdx.x * 256 + threadIdx.x;   // 262144 words = 1 MB, in-bounds for all dtypes
  unsigned int w = w1[i];
  u16t lo = (u16t)(w & 0xffffu), hi = (u16t)(w >> 16);
  float flo = bf2f(lo);
  int a = (!(fabsf(flo) < 0.25f)) ? 1 : 0;          // fires only for fp32 mantissa noise
  __half hh; *(u16t*)&hh = hi; float fhi = __half2float(hh);
  int b = (fabsf(fhi) > 0.25f && fabsf(fhi) < 256.f) ? 1 : 0;  // fires for bf16 patterns
  unsigned long long ba = __ballot(a), bb = __ballot(b);
  if ((threadIdx.x & 63) == 0) {
    atomicAdd(&cnts[0], (int)__popcll(ba));
    atomicAdd(&cnts[1], (int)__popcll(bb));
  }
}
__global__ void detect_finalize_k(const int* __restrict__ cnts, int* __restrict__ dflag) {
  if (threadIdx.x == 0)
    dflag[0] = (cnts[0] > 4096) ? 1 : ((cnts[1] < 4096) ? 2 : 0);
}

// ---------------- Mask layout probe: flag=1 if byte-packed ----------------
__global__ __launch_bounds__(256) void detect_mask_k(const unsigned int* __restrict__ msk,
                                                     int* __restrict__ flag) {
  int i = blockIdx.x * 256 + threadIdx.x;
  if (i < 12800) {                      // exactly 51200 bytes, safe for int8 & int32
    unsigned int v = msk[i];
    if (v > 1u) atomicOr(flag, 1);
  }
}

// ---------------- RMSNorm: one wave per row of 512, output bf16 ----------------
__global__ __launch_bounds__(256) void rmsnorm_k(const void* __restrict__ seq,
                                                 const void* __restrict__ w,
                                                 const int* __restrict__ dfp,
                                                 u16t* __restrict__ xn) {
  const int dt = dfp[0];
  int row = blockIdx.x * 4 + (threadIdx.x >> 6);
  int lane = threadIdx.x & 63;
  size_t base = (size_t)row * MODEL + lane * 8;
  float x[8]; float ss = 0.f;
  if (dt == 0) {
    u16x8 xv = *(const u16x8*)((const u16t*)seq + base);
#pragma unroll
    for (int j = 0; j < 8; j++) { x[j] = bf2f(xv[j]); ss += x[j] * x[j]; }
  } else {
#pragma unroll
    for (int j = 0; j < 8; j++) { x[j] = ldf(seq, base + j, dt); ss += x[j] * x[j]; }
  }
#pragma unroll
  for (int o = 32; o; o >>= 1) ss += __shfl_xor(ss, o);
  float rstd = rsqrtf(ss * (1.f / 512.f) + 1.1920929e-07f);
  u16x8 ov;
#pragma unroll
  for (int j = 0; j < 8; j++) ov[j] = f2bf(x[j] * rstd * ldf(w, lane * 8 + j, dt));
  *(u16x8*)(xn + base) = ov;
}

// ---------------- Transpose (R x C) -> (C x R) with dtype conversion to bf16 ----------------
__global__ __launch_bounds__(256) void transpose_k(const void* __restrict__ src,
                                                   u16t* __restrict__ dst,
                                                   const int* __restrict__ dfp,
                                                   int R, int C) {
  const int dt = dfp[0];
  __shared__ u16t tile[32][33];
  int x = threadIdx.x & 31, y = threadIdx.x >> 5;
  int c0 = blockIdx.x * 32, r0 = blockIdx.y * 32;
#pragma unroll
  for (int i = 0; i < 32; i += 8)
    tile[y + i][x] = f2bf(ldf(src, (size_t)(r0 + y + i) * C + c0 + x, dt));
  __syncthreads();
#pragma unroll
  for (int i = 0; i < 32; i += 8) dst[(size_t)(c0 + y + i) * R + r0 + x] = tile[x][y + i];
}

// ---------------- GEMM1: Act = silu(Xn@w1) * (Xn@w2), BM=128 BN=64 BK=64 ----------------
__global__ __launch_bounds__(256, 2) void ffn_gemm1(const u16t* __restrict__ Xn,
                                                    const u16t* __restrict__ W1t,
                                                    const u16t* __restrict__ W2t,
                                                    u16t* __restrict__ Act) {
  __shared__ u16t As[128 * 64];
  __shared__ u16t B1s[64 * 64];
  __shared__ u16t B2s[64 * 64];
  const int tid = threadIdx.x;
  const int lane = tid & 63;
  const int wave = tid >> 6;
  const int wr = wave >> 1, wc = wave & 1;
  const int quad = lane >> 4, l16 = lane & 15;
  const int mBase = blockIdx.x * 128;
  const int nBase = blockIdx.y * 64;
  const int wuBase = tid & ~63;

  f32x4 acc1[4][2], acc2[4][2];
  const f32x4 zf = {0.f, 0.f, 0.f, 0.f};
#pragma unroll
  for (int i = 0; i < 4; i++)
#pragma unroll
    for (int j = 0; j < 2; j++) { acc1[i][j] = zf; acc2[i][j] = zf; }

  for (int kt = 0; kt < MODEL; kt += 64) {
#pragma unroll
    for (int c = 0; c < 4; c++) {
      int chunk = c * 256 + tid;
      int r = chunk >> 3, k8 = (chunk & 7) << 3;
      gl2lds16(Xn + (size_t)(mBase + r) * MODEL + kt + k8, As + (size_t)(c * 256 + wuBase) * 8);
    }
#pragma unroll
    for (int c = 0; c < 2; c++) {
      int chunk = c * 256 + tid;
      int r = chunk >> 3, k8 = (chunk & 7) << 3;
      gl2lds16(W1t + (size_t)(nBase + r) * MODEL + kt + k8, B1s + (size_t)(c * 256 + wuBase) * 8);
      gl2lds16(W2t + (size_t)(nBase + r) * MODEL + kt + k8, B2s + (size_t)(c * 256 + wuBase) * 8);
    }
    __syncthreads();
#pragma unroll
    for (int ks = 0; ks < 64; ks += 32) {
      bf16x8 a[4], b1[2], b2[2];
#pragma unroll
      for (int mi = 0; mi < 4; mi++)
        a[mi] = *(const bf16x8*)(As + (wr * 64 + mi * 16 + l16) * 64 + ks + quad * 8);
#pragma unroll
      for (int ni = 0; ni < 2; ni++) {
        b1[ni] = *(const bf16x8*)(B1s + (wc * 32 + ni * 16 + l16) * 64 + ks + quad * 8);
        b2[ni] = *(const bf16x8*)(B2s + (wc * 32 + ni * 16 + l16) * 64 + ks + quad * 8);
      }
#pragma unroll
      for (int mi = 0; mi < 4; mi++)
#pragma unroll
        for (int ni = 0; ni < 2; ni++) {
          acc1[mi][ni] = __builtin_amdgcn_mfma_f32_16x16x32_bf16(a[mi], b1[ni], acc1[mi][ni], 0, 0, 0);
          acc2[mi][ni] = __builtin_amdgcn_mfma_f32_16x16x32_bf16(a[mi], b2[ni], acc2[mi][ni], 0, 0, 0);
        }
    }
    __syncthreads();
  }
#pragma unroll
  for (int mi = 0; mi < 4; mi++)
#pragma unroll
    for (int ni = 0; ni < 2; ni++)
#pragma unroll
      for (int r = 0; r < 4; r++) {
        int row = mBase + wr * 64 + mi * 16 + quad * 4 + r;
        int col = nBase + wc * 32 + ni * 16 + l16;
        float g1 = acc1[mi][ni][r], g2 = acc2[mi][ni][r];
        float sl = g1 / (1.f + __expf(-g1));
        Act[(size_t)row * FFNH + col] = f2bf(sl * g2);
      }
}

// ---------------- GEMM2: H = Act@w3 + seq, BM=128 BN=128 BK=64 ----------------
__global__ __launch_bounds__(256, 2) void ffn_gemm2(const u16t* __restrict__ Act,
                                                    const u16t* __restrict__ W3t,
                                                    const void* __restrict__ Seq,
                                                    const int* __restrict__ dfp,
                                                    u16t* __restrict__ H, int rowOff) {
  __shared__ u16t As[128 * 64];
  __shared__ u16t Bs[128 * 64];
  const int dt = dfp[0];
  const int tid = threadIdx.x;
  const int lane = tid & 63;
  const int wave = tid >> 6;
  const int wr = wave >> 1, wc = wave & 1;
  const int quad = lane >> 4, l16 = lane & 15;
  const int mBase = blockIdx.x * 128;
  const int nBase = blockIdx.y * 128;
  const int wuBase = tid & ~63;

  f32x4 acc[4][4];
  const f32x4 zf = {0.f, 0.f, 0.f, 0.f};
#pragma unroll
  for (int i = 0; i < 4; i++)
#pragma unroll
    for (int j = 0; j < 4; j++) acc[i][j] = zf;

  for (int kt = 0; kt < FFNH; kt += 64) {
#pragma unroll
    for (int c = 0; c < 4; c++) {
      int chunk = c * 256 + tid;
      int r = chunk >> 3, k8 = (chunk & 7) << 3;
      gl2lds16(Act + (size_t)(mBase + r) * FFNH + kt + k8, As + (size_t)(c * 256 + wuBase) * 8);
      gl2lds16(W3t + (size_t)(nBase + r) * FFNH + kt + k8, Bs + (size_t)(c * 256 + wuBase) * 8);
    }
    __syncthreads();
#pragma unroll
    for (int ks = 0; ks < 64; ks += 32) {
      bf16x8 a[4], b[4];
#pragma unroll
      for (int mi = 0; mi < 4; mi++)
        a[mi] = *(const bf16x8*)(As + (wr * 64 + mi * 16 + l16) * 64 + ks + quad * 8);
#pragma unroll
      for (int ni = 0; ni < 4; ni++)
        b[ni] = *(const bf16x8*)(Bs + (wc * 64 + ni * 16 + l16) * 64 + ks + quad * 8);
#pragma unroll
      for (int mi = 0; mi < 4; mi++)
#pragma unroll
        for (int ni = 0; ni < 4; ni++)
          acc[mi][ni] = __builtin_amdgcn_mfma_f32_16x16x32_bf16(a[mi], b[ni], acc[mi][ni], 0, 0, 0);
    }
    __syncthreads();
  }
#pragma unroll
  for (int mi = 0; mi < 4; mi++)
#pragma unroll
    for (int ni = 0; ni < 4; ni++)
#pragma unroll
      for (int r = 0; r < 4; r++) {
        int grow = rowOff + mBase + wr * 64 + mi * 16 + quad * 4 + r;
        int col = nBase + wc * 64 + ni * 16 + l16;
        float v = acc[mi][ni][r] + ldf(Seq, (size_t)grow * MODEL + col, dt);
        H[(size_t)grow * MODEL + col] = f2bf(v);
      }
}

// ---------------- Attention: one block per (b, head) ----------------
__global__ __launch_bounds__(256) void attn_k(const u16t* __restrict__ H,
                                              const void* __restrict__ q,
                                              const void* __restrict__ wk,
                                              const void* __restrict__ wv,
                                              const int* __restrict__ mask,
                                              const int* __restrict__ mflagp,
                                              const int* __restrict__ dfp,
                                              void* __restrict__ out) {
  const int b = blockIdx.x >> 3;
  const int n = blockIdx.x & 7;
  const int tid = threadIdx.x;
  const int w = tid >> 6;
  const int lane = tid & 63;
  const int T = 200;
  const int dt = dfp[0];
  const int mflag = mflagp[0];

  __shared__ float qkv[64];      // Wk @ q, later reused as ctxh
  __shared__ float sc[200];
  __shared__ float red1[4], red2[4];
  __shared__ float part[256];
  __shared__ u16t hbuf[200 * 64];

  if (tid < 64) {
    float s = 0.f;
#pragma unroll 8
    for (int e = 0; e < 64; e++)
      s += ldf(wk, (size_t)(n * 64 + tid) * 64 + e, dt) * ldf(q, (size_t)(b * 8 + n) * 64 + e, dt);
    qkv[tid] = s;
  }
  __syncthreads();

  float qkl = qkv[lane];
  for (int t = w; t < T; t += 4) {
    u16t hv = H[(size_t)(b * 200 + t) * MODEL + n * 64 + lane];
    hbuf[t * 64 + lane] = hv;
    float p = bf2f(hv) * qkl;
#pragma unroll
    for (int o = 32; o; o >>= 1) p += __shfl_xor(p, o);
    if (lane == 0) {
      int mv = mflag ? (int)((const unsigned char*)mask)[b * 200 + t]
                     : mask[b * 200 + t];
      sc[t] = mv ? p * 0.125f : -INFINITY;
    }
  }
  __syncthreads();

  // softmax over T
  float v = (tid < T) ? sc[tid] : -INFINITY;
  float mx = v;
#pragma unroll
  for (int o = 32; o; o >>= 1) mx = fmaxf(mx, __shfl_xor(mx, o));
  if (lane == 0) red1[w] = mx;
  __syncthreads();
  float gmax = fmaxf(fmaxf(red1[0], red1[1]), fmaxf(red1[2], red1[3]));
  float e;
  if (gmax == -INFINITY) {
    e = (tid == 0) ? 1.f : 0.f;   // NaN guard (reference guarantees mask[:,0]=True)
  } else {
    e = (tid < T) ? __expf(v - gmax) : 0.f;
  }
  float s = e;
#pragma unroll
  for (int o = 32; o; o >>= 1) s += __shfl_xor(s, o);
  if (lane == 0) red2[w] = s;
  __syncthreads();
  float inv = 1.f / (red2[0] + red2[1] + red2[2] + red2[3]);
  if (tid < T) sc[tid] = e * inv;
  __syncthreads();

  // ctxh[d] = sum_t prob[t] * h[t][d]
  float a2 = 0.f;
  for (int t = w; t < T; t += 4) a2 += sc[t] * bf2f(hbuf[t * 64 + lane]);
  part[w * 64 + lane] = a2;
  __syncthreads();
  if (tid < 64) qkv[tid] = part[tid] + part[64 + tid] + part[128 + tid] + part[192 + tid];
  __syncthreads();

  if (tid < 64) {
    float s2 = 0.f;
#pragma unroll 8
    for (int d = 0; d < 64; d++) s2 += qkv[d] * ldf(wv, (size_t)(n * 64 + d) * 64 + tid, dt);
    size_t oi = (size_t)(b * 8 + n) * 64 + tid;
    stf(out, oi, dt, s2 + ldf(q, oi, dt));
  }
}

extern "C" void kernel_launch(void* const* d_in, const int* in_sizes, int n_in,
                              void* d_out, int out_size, void* d_ws, size_t ws_size,
                              hipStream_t stream) {
  (void)in_sizes; (void)n_in; (void)out_size;
  const void* q   = d_in[0];
  const void* seq = d_in[1];
  const void* rw  = d_in[2];
  const void* w1  = d_in[3];
  const void* w2  = d_in[4];
  const void* w3  = d_in[5];
  const void* wk  = d_in[6];
  const void* wv  = d_in[7];
  const int*  msk = (const int*)d_in[8];

  char* ws = (char*)d_ws;
  size_t off = 0;
  auto alloc = [&](size_t b) { void* p = ws + off; off = (off + b + 255) & ~(size_t)255; return p; };
  int*  flags = (int*)alloc(512);            // [0]=mflag, [2]=cnts0, [3]=cnts1, [4]=dflag
  int*  mflag = flags + 0;
  int*  cnts  = flags + 2;
  int*  dflag = flags + 4;
  u16t* Xn  = (u16t*)alloc((size_t)BT_ROWS * MODEL * 2);   // reused as H in-place per chunk
  u16t* W1t = (u16t*)alloc((size_t)FFNH * MODEL * 2);
  u16t* W2t = (u16t*)alloc((size_t)FFNH * MODEL * 2);
  u16t* W3t = (u16t*)alloc((size_t)MODEL * FFNH * 2);
  size_t actBytes = (ws_size > off) ? (ws_size - off) : 0;
  long tpc = (long)(actBytes / ((size_t)128 * FFNH * 2));
  if (tpc < 1) tpc = 1;
  if (tpc > 400) tpc = 400;
  u16t* ActB = (u16t*)(ws + off);

  hipMemsetAsync(flags, 0, 512, stream);
  detect_dtype_k<<<dim3(1024), dim3(256), 0, stream>>>((const unsigned int*)w1, cnts);
  detect_finalize_k<<<dim3(1), dim3(64), 0, stream>>>(cnts, dflag);
  detect_mask_k<<<dim3(50), dim3(256), 0, stream>>>((const unsigned int*)msk, mflag);

  rmsnorm_k<<<dim3(BT_ROWS / 4), dim3(256), 0, stream>>>(seq, rw, dflag, Xn);
  transpose_k<<<dim3(FFNH / 32, MODEL / 32), dim3(256), 0, stream>>>(w1, W1t, dflag, MODEL, FFNH);
  transpose_k<<<dim3(FFNH / 32, MODEL / 32), dim3(256), 0, stream>>>(w2, W2t, dflag, MODEL, FFNH);
  transpose_k<<<dim3(MODEL / 32, FFNH / 32), dim3(256), 0, stream>>>(w3, W3t, dflag, FFNH, MODEL);

  for (int t0 = 0; t0 < 400; t0 += (int)tpc) {
    int tiles = (400 - t0 < (int)tpc) ? (400 - t0) : (int)tpc;
    int rows0 = t0 * 128;
    ffn_gemm1<<<dim3(tiles, FFNH / 64), dim3(256), 0, stream>>>(
        Xn + (size_t)rows0 * MODEL, W1t, W2t, ActB);
    ffn_gemm2<<<dim3(tiles, MODEL / 128), dim3(256), 0, stream>>>(
        ActB, W3t, seq, dflag, Xn, rows0);
  }
  attn_k<<<dim3(2048), dim3(256), 0, stream>>>(Xn, q, wk, wv, msk, mflag, dflag, d_out);
}

// Round 4
// 867.687 us; speedup vs baseline: 1.1608x; 1.1608x over previous
//
#include <hip/hip_runtime.h>
#include <hip/hip_fp16.h>
#include <cstdint>
#include <cstddef>

typedef unsigned short u16t;
typedef __bf16 bf16x8 __attribute__((ext_vector_type(8)));
typedef float f32x4 __attribute__((ext_vector_type(4)));
typedef unsigned short u16x8 __attribute__((ext_vector_type(8)));

#define BT_ROWS 51200   // B*T
#define MODEL 512
#define FFNH 2048

__device__ __forceinline__ float bf2f(u16t u) {
  union { unsigned int i; float f; } v; v.i = ((unsigned int)u) << 16; return v.f;
}
__device__ __forceinline__ u16t f2bf(float f) {
  union { float f; unsigned int i; } v; v.f = f;
  return (u16t)((v.i + 0x7fffu + ((v.i >> 16) & 1u)) >> 16);
}
// dt: 0 = bf16, 1 = fp32, 2 = fp16
__device__ __forceinline__ float ldf(const void* p, size_t i, int dt) {
  if (dt == 1) return ((const float*)p)[i];
  u16t u = ((const u16t*)p)[i];
  if (dt == 0) return bf2f(u);
  __half h; *(u16t*)&h = u; return __half2float(h);
}
__device__ __forceinline__ void stf(void* p, size_t i, int dt, float f) {
  if (dt == 1) { ((float*)p)[i] = f; }
  else if (dt == 0) { ((u16t*)p)[i] = f2bf(f); }
  else { __half h = __float2half(f); ((u16t*)p)[i] = *(u16t*)&h; }
}
__device__ __forceinline__ void gl2lds16(const void* g, void* l) {
  __builtin_amdgcn_global_load_lds((const __attribute__((address_space(1))) void*)g,
                                   (__attribute__((address_space(3))) void*)l, 16, 0, 0);
}

// ---------------- dtype probe on w1 (Xavier: |x| < 0.0485 in its own dtype) ----------------
__global__ __launch_bounds__(256) void detect_dtype_k(const unsigned int* __restrict__ w1,
                                                      int* __restrict__ cnts) {
  int i = blockIdx.x * 256 + threadIdx.x;   // 262144 words = 1 MB, in-bounds for all dtypes
  unsigned int w = w1[i];
  u16t lo = (u16t)(w & 0xffffu), hi = (u16t)(w >> 16);
  float flo = bf2f(lo);
  int a = (!(fabsf(flo) < 0.25f)) ? 1 : 0;          // fires only for fp32 mantissa noise
  __half hh; *(u16t*)&hh = hi; float fhi = __half2float(hh);
  int b = (fabsf(fhi) > 0.25f && fabsf(fhi) < 256.f) ? 1 : 0;  // fires for bf16 patterns
  unsigned long long ba = __ballot(a), bb = __ballot(b);
  if ((threadIdx.x & 63) == 0) {
    atomicAdd(&cnts[0], (int)__popcll(ba));
    atomicAdd(&cnts[1], (int)__popcll(bb));
  }
}
__global__ void detect_finalize_k(const int* __restrict__ cnts, int* __restrict__ dflag) {
  if (threadIdx.x == 0)
    dflag[0] = (cnts[0] > 4096) ? 1 : ((cnts[1] < 4096) ? 2 : 0);
}

// ---------------- Mask layout probe: flag=1 if byte-packed ----------------
__global__ __launch_bounds__(256) void detect_mask_k(const unsigned int* __restrict__ msk,
                                                     int* __restrict__ flag) {
  int i = blockIdx.x * 256 + threadIdx.x;
  if (i < 12800) {                      // exactly 51200 bytes, safe for int8 & int32
    unsigned int v = msk[i];
    if (v > 1u) atomicOr(flag, 1);
  }
}

// ---------------- RMSNorm: one wave per row of 512, output bf16 ----------------
__global__ __launch_bounds__(256) void rmsnorm_k(const void* __restrict__ seq,
                                                 const void* __restrict__ w,
                                                 const int* __restrict__ dfp,
                                                 u16t* __restrict__ xn) {
  const int dt = dfp[0];
  int row = blockIdx.x * 4 + (threadIdx.x >> 6);
  int lane = threadIdx.x & 63;
  size_t base = (size_t)row * MODEL + lane * 8;
  float x[8]; float ss = 0.f;
  if (dt == 0) {
    u16x8 xv = *(const u16x8*)((const u16t*)seq + base);
#pragma unroll
    for (int j = 0; j < 8; j++) { x[j] = bf2f(xv[j]); ss += x[j] * x[j]; }
  } else if (dt == 1) {
    const f32x4* p = (const f32x4*)((const float*)seq + base);
    f32x4 va = p[0], vb = p[1];
#pragma unroll
    for (int j = 0; j < 4; j++) { x[j] = va[j]; x[4 + j] = vb[j]; }
#pragma unroll
    for (int j = 0; j < 8; j++) ss += x[j] * x[j];
  } else {
#pragma unroll
    for (int j = 0; j < 8; j++) { x[j] = ldf(seq, base + j, dt); ss += x[j] * x[j]; }
  }
#pragma unroll
  for (int o = 32; o; o >>= 1) ss += __shfl_xor(ss, o);
  float rstd = rsqrtf(ss * (1.f / 512.f) + 1.1920929e-07f);
  u16x8 ov;
#pragma unroll
  for (int j = 0; j < 8; j++) ov[j] = f2bf(x[j] * rstd * ldf(w, lane * 8 + j, dt));
  *(u16x8*)(xn + base) = ov;
}

// ---------------- Transpose (R x C) -> (C x R) with dtype conversion to bf16 ----------------
__global__ __launch_bounds__(256) void transpose_k(const void* __restrict__ src,
                                                   u16t* __restrict__ dst,
                                                   const int* __restrict__ dfp,
                                                   int R, int C) {
  const int dt = dfp[0];
  __shared__ u16t tile[32][33];
  int x = threadIdx.x & 31, y = threadIdx.x >> 5;
  int c0 = blockIdx.x * 32, r0 = blockIdx.y * 32;
#pragma unroll
  for (int i = 0; i < 32; i += 8)
    tile[y + i][x] = f2bf(ldf(src, (size_t)(r0 + y + i) * C + c0 + x, dt));
  __syncthreads();
#pragma unroll
  for (int i = 0; i < 32; i += 8) dst[(size_t)(c0 + y + i) * R + r0 + x] = tile[x][y + i];
}

// LDS K-group XOR swizzle: physical group = logical ^ (row & 7). 2-way banks (free)
// instead of 16-way. Staging permutes the SOURCE k-group so data lands swizzled.

// ---------------- GEMM1: Act = silu(Xn@w1) * (Xn@w2), BM=128 BN=64 BK=64 ----------------
__global__ __launch_bounds__(256, 2) void ffn_gemm1(const u16t* __restrict__ Xn,
                                                    const u16t* __restrict__ W1t,
                                                    const u16t* __restrict__ W2t,
                                                    u16t* __restrict__ Act) {
  __shared__ u16t As[128 * 64];
  __shared__ u16t B1s[64 * 64];
  __shared__ u16t B2s[64 * 64];
  const int tid = threadIdx.x;
  const int lane = tid & 63;
  const int wave = tid >> 6;
  const int wr = wave >> 1, wc = wave & 1;
  const int quad = lane >> 4, l16 = lane & 15;
  const int nBase = blockIdx.x * 64;    // N-fastest for A-tile L2 locality
  const int mBase = blockIdx.y * 128;
  const int wuBase = tid & ~63;

  f32x4 acc1[4][2], acc2[4][2];
  const f32x4 zf = {0.f, 0.f, 0.f, 0.f};
#pragma unroll
  for (int i = 0; i < 4; i++)
#pragma unroll
    for (int j = 0; j < 2; j++) { acc1[i][j] = zf; acc2[i][j] = zf; }

  for (int kt = 0; kt < MODEL; kt += 64) {
#pragma unroll
    for (int c = 0; c < 4; c++) {
      int chunk = c * 256 + tid;
      int r = chunk >> 3, k8 = (chunk & 7) ^ (r & 7);   // swizzled source k-group
      gl2lds16(Xn + (size_t)(mBase + r) * MODEL + kt + k8 * 8, As + (size_t)(c * 256 + wuBase) * 8);
    }
#pragma unroll
    for (int c = 0; c < 2; c++) {
      int chunk = c * 256 + tid;
      int r = chunk >> 3, k8 = (chunk & 7) ^ (r & 7);
      gl2lds16(W1t + (size_t)(nBase + r) * MODEL + kt + k8 * 8, B1s + (size_t)(c * 256 + wuBase) * 8);
      gl2lds16(W2t + (size_t)(nBase + r) * MODEL + kt + k8 * 8, B2s + (size_t)(c * 256 + wuBase) * 8);
    }
    __syncthreads();
#pragma unroll
    for (int ks = 0; ks < 64; ks += 32) {
      bf16x8 a[4], b1[2], b2[2];
      const int sw = (ks >> 3) + quad;   // logical k-group
#pragma unroll
      for (int mi = 0; mi < 4; mi++) {
        int row = wr * 64 + mi * 16 + l16;
        a[mi] = *(const bf16x8*)(As + row * 64 + ((sw ^ (row & 7)) << 3));
      }
#pragma unroll
      for (int ni = 0; ni < 2; ni++) {
        int row = wc * 32 + ni * 16 + l16;
        b1[ni] = *(const bf16x8*)(B1s + row * 64 + ((sw ^ (row & 7)) << 3));
        b2[ni] = *(const bf16x8*)(B2s + row * 64 + ((sw ^ (row & 7)) << 3));
      }
#pragma unroll
      for (int mi = 0; mi < 4; mi++)
#pragma unroll
        for (int ni = 0; ni < 2; ni++) {
          acc1[mi][ni] = __builtin_amdgcn_mfma_f32_16x16x32_bf16(a[mi], b1[ni], acc1[mi][ni], 0, 0, 0);
          acc2[mi][ni] = __builtin_amdgcn_mfma_f32_16x16x32_bf16(a[mi], b2[ni], acc2[mi][ni], 0, 0, 0);
        }
    }
    __syncthreads();
  }
#pragma unroll
  for (int mi = 0; mi < 4; mi++)
#pragma unroll
    for (int ni = 0; ni < 2; ni++)
#pragma unroll
      for (int r = 0; r < 4; r++) {
        int row = mBase + wr * 64 + mi * 16 + quad * 4 + r;
        int col = nBase + wc * 32 + ni * 16 + l16;
        float g1 = acc1[mi][ni][r], g2 = acc2[mi][ni][r];
        float sl = g1 / (1.f + __expf(-g1));
        Act[(size_t)row * FFNH + col] = f2bf(sl * g2);
      }
}

// ---------------- GEMM2: H = Act@w3 + seq, BM=128 BN=128 BK=64 ----------------
__global__ __launch_bounds__(256, 2) void ffn_gemm2(const u16t* __restrict__ Act,
                                                    const u16t* __restrict__ W3t,
                                                    const void* __restrict__ Seq,
                                                    const int* __restrict__ dfp,
                                                    u16t* __restrict__ H, int rowOff) {
  __shared__ u16t As[128 * 64];
  __shared__ u16t Bs[128 * 64];
  const int dt = dfp[0];
  const int tid = threadIdx.x;
  const int lane = tid & 63;
  const int wave = tid >> 6;
  const int wr = wave >> 1, wc = wave & 1;
  const int quad = lane >> 4, l16 = lane & 15;
  const int nBase = blockIdx.x * 128;   // N-fastest
  const int mBase = blockIdx.y * 128;
  const int wuBase = tid & ~63;

  f32x4 acc[4][4];
  const f32x4 zf = {0.f, 0.f, 0.f, 0.f};
#pragma unroll
  for (int i = 0; i < 4; i++)
#pragma unroll
    for (int j = 0; j < 4; j++) acc[i][j] = zf;

  for (int kt = 0; kt < FFNH; kt += 64) {
#pragma unroll
    for (int c = 0; c < 4; c++) {
      int chunk = c * 256 + tid;
      int r = chunk >> 3, k8 = (chunk & 7) ^ (r & 7);
      gl2lds16(Act + (size_t)(mBase + r) * FFNH + kt + k8 * 8, As + (size_t)(c * 256 + wuBase) * 8);
      gl2lds16(W3t + (size_t)(nBase + r) * FFNH + kt + k8 * 8, Bs + (size_t)(c * 256 + wuBase) * 8);
    }
    __syncthreads();
#pragma unroll
    for (int ks = 0; ks < 64; ks += 32) {
      bf16x8 a[4], b[4];
      const int sw = (ks >> 3) + quad;
#pragma unroll
      for (int mi = 0; mi < 4; mi++) {
        int row = wr * 64 + mi * 16 + l16;
        a[mi] = *(const bf16x8*)(As + row * 64 + ((sw ^ (row & 7)) << 3));
      }
#pragma unroll
      for (int ni = 0; ni < 4; ni++) {
        int row = wc * 64 + ni * 16 + l16;
        b[ni] = *(const bf16x8*)(Bs + row * 64 + ((sw ^ (row & 7)) << 3));
      }
#pragma unroll
      for (int mi = 0; mi < 4; mi++)
#pragma unroll
        for (int ni = 0; ni < 4; ni++)
          acc[mi][ni] = __builtin_amdgcn_mfma_f32_16x16x32_bf16(a[mi], b[ni], acc[mi][ni], 0, 0, 0);
    }
    __syncthreads();
  }
#pragma unroll
  for (int mi = 0; mi < 4; mi++)
#pragma unroll
    for (int ni = 0; ni < 4; ni++)
#pragma unroll
      for (int r = 0; r < 4; r++) {
        int grow = rowOff + mBase + wr * 64 + mi * 16 + quad * 4 + r;
        int col = nBase + wc * 64 + ni * 16 + l16;
        float v = acc[mi][ni][r] + ldf(Seq, (size_t)grow * MODEL + col, dt);
        H[(size_t)grow * MODEL + col] = f2bf(v);
      }
}

// ---------------- Attention: one block per (b, head) ----------------
__global__ __launch_bounds__(256) void attn_k(const u16t* __restrict__ H,
                                              const void* __restrict__ q,
                                              const void* __restrict__ wk,
                                              const void* __restrict__ wv,
                                              const int* __restrict__ mask,
                                              const int* __restrict__ mflagp,
                                              const int* __restrict__ dfp,
                                              void* __restrict__ out) {
  const int b = blockIdx.x >> 3;
  const int n = blockIdx.x & 7;
  const int tid = threadIdx.x;
  const int w = tid >> 6;
  const int lane = tid & 63;
  const int T = 200;
  const int dt = dfp[0];
  const int mflag = mflagp[0];

  __shared__ float qkv[64];      // Wk @ q, later reused as ctxh
  __shared__ float sc[200];
  __shared__ float red1[4], red2[4];
  __shared__ float part[256];
  __shared__ u16t hbuf[200 * 64];

  if (tid < 64) {
    float s = 0.f;
#pragma unroll 8
    for (int e = 0; e < 64; e++)
      s += ldf(wk, (size_t)(n * 64 + tid) * 64 + e, dt) * ldf(q, (size_t)(b * 8 + n) * 64 + e, dt);
    qkv[tid] = s;
  }
  __syncthreads();

  float qkl = qkv[lane];
  for (int t = w; t < T; t += 4) {
    u16t hv = H[(size_t)(b * 200 + t) * MODEL + n * 64 + lane];
    hbuf[t * 64 + lane] = hv;
    float p = bf2f(hv) * qkl;
#pragma unroll
    for (int o = 32; o; o >>= 1) p += __shfl_xor(p, o);
    if (lane == 0) {
      int mv = mflag ? (int)((const unsigned char*)mask)[b * 200 + t]
                     : mask[b * 200 + t];
      sc[t] = mv ? p * 0.125f : -INFINITY;
    }
  }
  __syncthreads();

  // softmax over T
  float v = (tid < T) ? sc[tid] : -INFINITY;
  float mx = v;
#pragma unroll
  for (int o = 32; o; o >>= 1) mx = fmaxf(mx, __shfl_xor(mx, o));
  if (lane == 0) red1[w] = mx;
  __syncthreads();
  float gmax = fmaxf(fmaxf(red1[0], red1[1]), fmaxf(red1[2], red1[3]));
  float e;
  if (gmax == -INFINITY) {
    e = (tid == 0) ? 1.f : 0.f;   // NaN guard (reference guarantees mask[:,0]=True)
  } else {
    e = (tid < T) ? __expf(v - gmax) : 0.f;
  }
  float s = e;
#pragma unroll
  for (int o = 32; o; o >>= 1) s += __shfl_xor(s, o);
  if (lane == 0) red2[w] = s;
  __syncthreads();
  float inv = 1.f / (red2[0] + red2[1] + red2[2] + red2[3]);
  if (tid < T) sc[tid] = e * inv;
  __syncthreads();

  // ctxh[d] = sum_t prob[t] * h[t][d]
  float a2 = 0.f;
  for (int t = w; t < T; t += 4) a2 += sc[t] * bf2f(hbuf[t * 64 + lane]);
  part[w * 64 + lane] = a2;
  __syncthreads();
  if (tid < 64) qkv[tid] = part[tid] + part[64 + tid] + part[128 + tid] + part[192 + tid];
  __syncthreads();

  if (tid < 64) {
    float s2 = 0.f;
#pragma unroll 8
    for (int d = 0; d < 64; d++) s2 += qkv[d] * ldf(wv, (size_t)(n * 64 + d) * 64 + tid, dt);
    size_t oi = (size_t)(b * 8 + n) * 64 + tid;
    stf(out, oi, dt, s2 + ldf(q, oi, dt));
  }
}

extern "C" void kernel_launch(void* const* d_in, const int* in_sizes, int n_in,
                              void* d_out, int out_size, void* d_ws, size_t ws_size,
                              hipStream_t stream) {
  (void)in_sizes; (void)n_in; (void)out_size;
  const void* q   = d_in[0];
  const void* seq = d_in[1];
  const void* rw  = d_in[2];
  const void* w1  = d_in[3];
  const void* w2  = d_in[4];
  const void* w3  = d_in[5];
  const void* wk  = d_in[6];
  const void* wv  = d_in[7];
  const int*  msk = (const int*)d_in[8];

  char* ws = (char*)d_ws;
  size_t off = 0;
  auto alloc = [&](size_t b) { void* p = ws + off; off = (off + b + 255) & ~(size_t)255; return p; };
  int*  flags = (int*)alloc(512);            // [0]=mflag, [2]=cnts0, [3]=cnts1, [4]=dflag
  int*  mflag = flags + 0;
  int*  cnts  = flags + 2;
  int*  dflag = flags + 4;
  u16t* Xn  = (u16t*)alloc((size_t)BT_ROWS * MODEL * 2);   // reused as H in-place per chunk
  u16t* W1t = (u16t*)alloc((size_t)FFNH * MODEL * 2);
  u16t* W2t = (u16t*)alloc((size_t)FFNH * MODEL * 2);
  u16t* W3t = (u16t*)alloc((size_t)MODEL * FFNH * 2);
  size_t actBytes = (ws_size > off) ? (ws_size - off) : 0;
  long tpc = (long)(actBytes / ((size_t)128 * FFNH * 2));
  if (tpc < 1) tpc = 1;
  if (tpc > 100) tpc = 100;   // 100 tiles -> 50 MB Act chunk, stays L3-resident gemm1->gemm2
  u16t* ActB = (u16t*)(ws + off);

  hipMemsetAsync(flags, 0, 512, stream);
  detect_dtype_k<<<dim3(1024), dim3(256), 0, stream>>>((const unsigned int*)w1, cnts);
  detect_finalize_k<<<dim3(1), dim3(64), 0, stream>>>(cnts, dflag);
  detect_mask_k<<<dim3(50), dim3(256), 0, stream>>>((const unsigned int*)msk, mflag);

  rmsnorm_k<<<dim3(BT_ROWS / 4), dim3(256), 0, stream>>>(seq, rw, dflag, Xn);
  transpose_k<<<dim3(FFNH / 32, MODEL / 32), dim3(256), 0, stream>>>(w1, W1t, dflag, MODEL, FFNH);
  transpose_k<<<dim3(FFNH / 32, MODEL / 32), dim3(256), 0, stream>>>(w2, W2t, dflag, MODEL, FFNH);
  transpose_k<<<dim3(MODEL / 32, FFNH / 32), dim3(256), 0, stream>>>(w3, W3t, dflag, FFNH, MODEL);

  for (int t0 = 0; t0 < 400; t0 += (int)tpc) {
    int tiles = (400 - t0 < (int)tpc) ? (400 - t0) : (int)tpc;
    int rows0 = t0 * 128;
    ffn_gemm1<<<dim3(FFNH / 64, tiles), dim3(256), 0, stream>>>(
        Xn + (size_t)rows0 * MODEL, W1t, W2t, ActB);
    ffn_gemm2<<<dim3(MODEL / 128, tiles), dim3(256), 0, stream>>>(
        ActB, W3t, seq, dflag, Xn, rows0);
  }
  attn_k<<<dim3(2048), dim3(256), 0, stream>>>(Xn, q, wk, wv, msk, mflag, dflag, d_out);
}

// Round 5
// 787.669 us; speedup vs baseline: 1.2787x; 1.1016x over previous
//
#include <hip/hip_runtime.h>
#include <hip/hip_fp16.h>
#include <cstdint>
#include <cstddef>

typedef unsigned short u16t;
typedef __bf16 bf16x8 __attribute__((ext_vector_type(8)));
typedef float f32x4 __attribute__((ext_vector_type(4)));
typedef unsigned short u16x8 __attribute__((ext_vector_type(8)));

#define BT_ROWS 51200   // B*T
#define MODEL 512
#define FFNH 2048

__device__ __forceinline__ float bf2f(u16t u) {
  union { unsigned int i; float f; } v; v.i = ((unsigned int)u) << 16; return v.f;
}
__device__ __forceinline__ u16t f2bf(float f) {
  union { float f; unsigned int i; } v; v.f = f;
  return (u16t)((v.i + 0x7fffu + ((v.i >> 16) & 1u)) >> 16);
}
// dt: 0 = bf16, 1 = fp32, 2 = fp16
__device__ __forceinline__ float ldf(const void* p, size_t i, int dt) {
  if (dt == 1) return ((const float*)p)[i];
  u16t u = ((const u16t*)p)[i];
  if (dt == 0) return bf2f(u);
  __half h; *(u16t*)&h = u; return __half2float(h);
}
__device__ __forceinline__ void stf(void* p, size_t i, int dt, float f) {
  if (dt == 1) { ((float*)p)[i] = f; }
  else if (dt == 0) { ((u16t*)p)[i] = f2bf(f); }
  else { __half h = __float2half(f); ((u16t*)p)[i] = *(u16t*)&h; }
}
__device__ __forceinline__ void gl2lds16(const void* g, void* l) {
  __builtin_amdgcn_global_load_lds((const __attribute__((address_space(1))) void*)g,
                                   (__attribute__((address_space(3))) void*)l, 16, 0, 0);
}

// ---------------- dtype probe on w1 (Xavier: |x| < 0.0485 in its own dtype) ----------------
__global__ __launch_bounds__(256) void detect_dtype_k(const unsigned int* __restrict__ w1,
                                                      int* __restrict__ cnts) {
  int i = blockIdx.x * 256 + threadIdx.x;   // 262144 words = 1 MB, in-bounds for all dtypes
  unsigned int w = w1[i];
  u16t lo = (u16t)(w & 0xffffu), hi = (u16t)(w >> 16);
  float flo = bf2f(lo);
  int a = (!(fabsf(flo) < 0.25f)) ? 1 : 0;          // fires only for fp32 mantissa noise
  __half hh; *(u16t*)&hh = hi; float fhi = __half2float(hh);
  int b = (fabsf(fhi) > 0.25f && fabsf(fhi) < 256.f) ? 1 : 0;  // fires for bf16 patterns
  unsigned long long ba = __ballot(a), bb = __ballot(b);
  if ((threadIdx.x & 63) == 0) {
    atomicAdd(&cnts[0], (int)__popcll(ba));
    atomicAdd(&cnts[1], (int)__popcll(bb));
  }
}
__global__ void detect_finalize_k(const int* __restrict__ cnts, int* __restrict__ dflag) {
  if (threadIdx.x == 0)
    dflag[0] = (cnts[0] > 4096) ? 1 : ((cnts[1] < 4096) ? 2 : 0);
}

// ---------------- Mask layout probe: flag=1 if byte-packed ----------------
__global__ __launch_bounds__(256) void detect_mask_k(const unsigned int* __restrict__ msk,
                                                     int* __restrict__ flag) {
  int i = blockIdx.x * 256 + threadIdx.x;
  if (i < 12800) {                      // exactly 51200 bytes, safe for int8 & int32
    unsigned int v = msk[i];
    if (v > 1u) atomicOr(flag, 1);
  }
}

// ---------------- RMSNorm: one wave per row of 512, output bf16 ----------------
__global__ __launch_bounds__(256) void rmsnorm_k(const void* __restrict__ seq,
                                                 const void* __restrict__ w,
                                                 const int* __restrict__ dfp,
                                                 u16t* __restrict__ xn) {
  const int dt = dfp[0];
  int row = blockIdx.x * 4 + (threadIdx.x >> 6);
  int lane = threadIdx.x & 63;
  size_t base = (size_t)row * MODEL + lane * 8;
  float x[8]; float ss = 0.f;
  if (dt == 0) {
    u16x8 xv = *(const u16x8*)((const u16t*)seq + base);
#pragma unroll
    for (int j = 0; j < 8; j++) { x[j] = bf2f(xv[j]); ss += x[j] * x[j]; }
  } else if (dt == 1) {
    const f32x4* p = (const f32x4*)((const float*)seq + base);
    f32x4 va = p[0], vb = p[1];
#pragma unroll
    for (int j = 0; j < 4; j++) { x[j] = va[j]; x[4 + j] = vb[j]; }
#pragma unroll
    for (int j = 0; j < 8; j++) ss += x[j] * x[j];
  } else {
#pragma unroll
    for (int j = 0; j < 8; j++) { x[j] = ldf(seq, base + j, dt); ss += x[j] * x[j]; }
  }
#pragma unroll
  for (int o = 32; o; o >>= 1) ss += __shfl_xor(ss, o);
  float rstd = rsqrtf(ss * (1.f / 512.f) + 1.1920929e-07f);
  u16x8 ov;
#pragma unroll
  for (int j = 0; j < 8; j++) ov[j] = f2bf(x[j] * rstd * ldf(w, lane * 8 + j, dt));
  *(u16x8*)(xn + base) = ov;
}

// ---------------- Transpose (R x C) -> (C x R) with dtype conversion to bf16 ----------------
__global__ __launch_bounds__(256) void transpose_k(const void* __restrict__ src,
                                                   u16t* __restrict__ dst,
                                                   const int* __restrict__ dfp,
                                                   int R, int C) {
  const int dt = dfp[0];
  __shared__ u16t tile[32][33];
  int x = threadIdx.x & 31, y = threadIdx.x >> 5;
  int c0 = blockIdx.x * 32, r0 = blockIdx.y * 32;
#pragma unroll
  for (int i = 0; i < 32; i += 8)
    tile[y + i][x] = f2bf(ldf(src, (size_t)(r0 + y + i) * C + c0 + x, dt));
  __syncthreads();
#pragma unroll
  for (int i = 0; i < 32; i += 8) dst[(size_t)(c0 + y + i) * R + r0 + x] = tile[x][y + i];
}

// LDS K-group XOR swizzle: physical group = logical ^ (row & 7). 2-way banks (free)
// instead of 16-way. Staging permutes the SOURCE k-group so data lands swizzled.

// ---------------- GEMM1: Act = silu(Xn@w1) * (Xn@w2), BM=128 BN=64 BK=64 ----------------
__global__ __launch_bounds__(256, 2) void ffn_gemm1(const u16t* __restrict__ Xn,
                                                    const u16t* __restrict__ W1t,
                                                    const u16t* __restrict__ W2t,
                                                    u16t* __restrict__ Act) {
  __shared__ u16t As[128 * 64];
  __shared__ u16t B1s[64 * 64];
  __shared__ u16t B2s[64 * 64];
  const int tid = threadIdx.x;
  const int lane = tid & 63;
  const int wave = tid >> 6;
  const int wr = wave >> 1, wc = wave & 1;
  const int quad = lane >> 4, l16 = lane & 15;
  const int nBase = blockIdx.x * 64;    // N-fastest for A-tile L2 locality
  const int mBase = blockIdx.y * 128;
  const int wuBase = tid & ~63;

  f32x4 acc1[4][2], acc2[4][2];
  const f32x4 zf = {0.f, 0.f, 0.f, 0.f};
#pragma unroll
  for (int i = 0; i < 4; i++)
#pragma unroll
    for (int j = 0; j < 2; j++) { acc1[i][j] = zf; acc2[i][j] = zf; }

  for (int kt = 0; kt < MODEL; kt += 64) {
#pragma unroll
    for (int c = 0; c < 4; c++) {
      int chunk = c * 256 + tid;
      int r = chunk >> 3, k8 = (chunk & 7) ^ (r & 7);   // swizzled source k-group
      gl2lds16(Xn + (size_t)(mBase + r) * MODEL + kt + k8 * 8, As + (size_t)(c * 256 + wuBase) * 8);
    }
#pragma unroll
    for (int c = 0; c < 2; c++) {
      int chunk = c * 256 + tid;
      int r = chunk >> 3, k8 = (chunk & 7) ^ (r & 7);
      gl2lds16(W1t + (size_t)(nBase + r) * MODEL + kt + k8 * 8, B1s + (size_t)(c * 256 + wuBase) * 8);
      gl2lds16(W2t + (size_t)(nBase + r) * MODEL + kt + k8 * 8, B2s + (size_t)(c * 256 + wuBase) * 8);
    }
    __syncthreads();
#pragma unroll
    for (int ks = 0; ks < 64; ks += 32) {
      bf16x8 a[4], b1[2], b2[2];
      const int sw = (ks >> 3) + quad;   // logical k-group
#pragma unroll
      for (int mi = 0; mi < 4; mi++) {
        int row = wr * 64 + mi * 16 + l16;
        a[mi] = *(const bf16x8*)(As + row * 64 + ((sw ^ (row & 7)) << 3));
      }
#pragma unroll
      for (int ni = 0; ni < 2; ni++) {
        int row = wc * 32 + ni * 16 + l16;
        b1[ni] = *(const bf16x8*)(B1s + row * 64 + ((sw ^ (row & 7)) << 3));
        b2[ni] = *(const bf16x8*)(B2s + row * 64 + ((sw ^ (row & 7)) << 3));
      }
#pragma unroll
      for (int mi = 0; mi < 4; mi++)
#pragma unroll
        for (int ni = 0; ni < 2; ni++) {
          acc1[mi][ni] = __builtin_amdgcn_mfma_f32_16x16x32_bf16(a[mi], b1[ni], acc1[mi][ni], 0, 0, 0);
          acc2[mi][ni] = __builtin_amdgcn_mfma_f32_16x16x32_bf16(a[mi], b2[ni], acc2[mi][ni], 0, 0, 0);
        }
    }
    __syncthreads();
  }
#pragma unroll
  for (int mi = 0; mi < 4; mi++)
#pragma unroll
    for (int ni = 0; ni < 2; ni++)
#pragma unroll
      for (int r = 0; r < 4; r++) {
        int row = mBase + wr * 64 + mi * 16 + quad * 4 + r;
        int col = nBase + wc * 32 + ni * 16 + l16;
        float g1 = acc1[mi][ni][r], g2 = acc2[mi][ni][r];
        float sl = g1 / (1.f + __expf(-g1));
        Act[(size_t)row * FFNH + col] = f2bf(sl * g2);
      }
}

// ---------------- GEMM2: H = Act@w3 + seq, BM=128 BN=128 BK=64 ----------------
__global__ __launch_bounds__(256, 2) void ffn_gemm2(const u16t* __restrict__ Act,
                                                    const u16t* __restrict__ W3t,
                                                    const void* __restrict__ Seq,
                                                    const int* __restrict__ dfp,
                                                    u16t* __restrict__ H, int rowOff) {
  __shared__ u16t As[128 * 64];
  __shared__ u16t Bs[128 * 64];
  const int dt = dfp[0];
  const int tid = threadIdx.x;
  const int lane = tid & 63;
  const int wave = tid >> 6;
  const int wr = wave >> 1, wc = wave & 1;
  const int quad = lane >> 4, l16 = lane & 15;
  const int nBase = blockIdx.x * 128;   // N-fastest
  const int mBase = blockIdx.y * 128;
  const int wuBase = tid & ~63;

  f32x4 acc[4][4];
  const f32x4 zf = {0.f, 0.f, 0.f, 0.f};
#pragma unroll
  for (int i = 0; i < 4; i++)
#pragma unroll
    for (int j = 0; j < 4; j++) acc[i][j] = zf;

  for (int kt = 0; kt < FFNH; kt += 64) {
#pragma unroll
    for (int c = 0; c < 4; c++) {
      int chunk = c * 256 + tid;
      int r = chunk >> 3, k8 = (chunk & 7) ^ (r & 7);
      gl2lds16(Act + (size_t)(mBase + r) * FFNH + kt + k8 * 8, As + (size_t)(c * 256 + wuBase) * 8);
      gl2lds16(W3t + (size_t)(nBase + r) * FFNH + kt + k8 * 8, Bs + (size_t)(c * 256 + wuBase) * 8);
    }
    __syncthreads();
#pragma unroll
    for (int ks = 0; ks < 64; ks += 32) {
      bf16x8 a[4], b[4];
      const int sw = (ks >> 3) + quad;
#pragma unroll
      for (int mi = 0; mi < 4; mi++) {
        int row = wr * 64 + mi * 16 + l16;
        a[mi] = *(const bf16x8*)(As + row * 64 + ((sw ^ (row & 7)) << 3));
      }
#pragma unroll
      for (int ni = 0; ni < 4; ni++) {
        int row = wc * 64 + ni * 16 + l16;
        b[ni] = *(const bf16x8*)(Bs + row * 64 + ((sw ^ (row & 7)) << 3));
      }
#pragma unroll
      for (int mi = 0; mi < 4; mi++)
#pragma unroll
        for (int ni = 0; ni < 4; ni++)
          acc[mi][ni] = __builtin_amdgcn_mfma_f32_16x16x32_bf16(a[mi], b[ni], acc[mi][ni], 0, 0, 0);
    }
    __syncthreads();
  }
#pragma unroll
  for (int mi = 0; mi < 4; mi++)
#pragma unroll
    for (int ni = 0; ni < 4; ni++)
#pragma unroll
      for (int r = 0; r < 4; r++) {
        int grow = rowOff + mBase + wr * 64 + mi * 16 + quad * 4 + r;
        int col = nBase + wc * 64 + ni * 16 + l16;
        float v = acc[mi][ni][r] + ldf(Seq, (size_t)grow * MODEL + col, dt);
        H[(size_t)grow * MODEL + col] = f2bf(v);
      }
}

// ---------------- Attention: one block per (b, head), data-parallel phases ----------------
// LDS row stride 66 u16 -> bank = (t + d/2) % 32 : 2-way in both read phases (free).
__global__ __launch_bounds__(256) void attn_k(const u16t* __restrict__ H,
                                              const void* __restrict__ q,
                                              const void* __restrict__ wk,
                                              const void* __restrict__ wv,
                                              const int* __restrict__ mask,
                                              const int* __restrict__ mflagp,
                                              const int* __restrict__ dfp,
                                              void* __restrict__ out) {
  const int b = blockIdx.x >> 3;
  const int n = blockIdx.x & 7;
  const int tid = threadIdx.x;
  const int w = tid >> 6;
  const int lane = tid & 63;
  const int T = 200;
  const int HS = 66;
  const int dt = dfp[0];
  const int mflag = mflagp[0];

  __shared__ u16t hbuf[200 * HS];   // 26.4 KB
  __shared__ float qk[64];
  __shared__ float sc[200];
  __shared__ float part[256];
  __shared__ float red[8];
  __shared__ float ctx[64];

  // ---- stage H slice: coalesced u16x8 global reads, scalar LDS writes ----
  for (int chunk = tid; chunk < 1600; chunk += 256) {
    int r = chunk >> 3, c = (chunk & 7) << 3;
    u16x8 v = *(const u16x8*)(H + (size_t)(b * 200 + r) * MODEL + n * 64 + c);
#pragma unroll
    for (int j = 0; j < 8; j++) hbuf[r * HS + c + j] = v[j];
  }

  // ---- qk[d] = sum_e wk[n][d][e] * q[b][n][e] ; 4 threads per output d ----
  {
    int d = tid >> 2, sub = tid & 3;
    float s = 0.f;
    size_t wb = ((size_t)n * 64 + d) * 64 + sub * 16;
    size_t qb = (size_t)(b * 8 + n) * 64 + sub * 16;
#pragma unroll
    for (int i = 0; i < 16; i++) s += ldf(wk, wb + i, dt) * ldf(q, qb + i, dt);
    part[tid] = s;
  }
  __syncthreads();
  if (tid < 64) qk[tid] = part[tid * 4] + part[tid * 4 + 1] + part[tid * 4 + 2] + part[tid * 4 + 3];
  __syncthreads();

  // ---- scores: thread t does 64 LDS FMAs (qk[] is broadcast) ----
  float sv = -INFINITY;
  if (tid < T) {
    float s = 0.f;
#pragma unroll 16
    for (int d = 0; d < 64; d++) s += bf2f(hbuf[tid * HS + d]) * qk[d];
    int mv = mflag ? (int)((const unsigned char*)mask)[b * 200 + tid] : mask[b * 200 + tid];
    sv = mv ? s * 0.125f : -INFINITY;
  }

  // ---- softmax over T ----
  float mx = sv;
#pragma unroll
  for (int o = 32; o; o >>= 1) mx = fmaxf(mx, __shfl_xor(mx, o));
  if (lane == 0) red[w] = mx;
  __syncthreads();
  float gmax = fmaxf(fmaxf(red[0], red[1]), fmaxf(red[2], red[3]));
  float e = 0.f;
  if (gmax == -INFINITY) {
    if (tid == 0) e = 1.f;              // NaN guard (reference guarantees mask[:,0]=True)
  } else if (tid < T) {
    e = __expf(sv - gmax);
  }
  float s = e;
#pragma unroll
  for (int o = 32; o; o >>= 1) s += __shfl_xor(s, o);
  if (lane == 0) red[4 + w] = s;
  __syncthreads();
  float inv = 1.f / (red[4] + red[5] + red[6] + red[7]);
  if (tid < T) sc[tid] = e * inv;
  __syncthreads();

  // ---- ctx[d] = sum_t p[t] * h[t][d] ; wave w covers t = w::4 ----
  float a2 = 0.f;
  for (int t = w; t < T; t += 4) a2 += sc[t] * bf2f(hbuf[t * HS + lane]);
  part[tid] = a2;
  __syncthreads();
  if (tid < 64) ctx[tid] = part[tid] + part[64 + tid] + part[128 + tid] + part[192 + tid];
  __syncthreads();

  // ---- out = ctx @ wv + q ; wave w covers d = w*16..w*16+15 ----
  {
    int od = tid & 63;
    float s2 = 0.f;
#pragma unroll
    for (int i = 0; i < 16; i++) {
      int d = w * 16 + i;
      s2 += ctx[d] * ldf(wv, ((size_t)n * 64 + d) * 64 + od, dt);
    }
    part[tid] = s2;
  }
  __syncthreads();
  if (tid < 64) {
    size_t oi = (size_t)(b * 8 + n) * 64 + tid;
    stf(out, oi, dt,
        part[tid] + part[64 + tid] + part[128 + tid] + part[192 + tid] + ldf(q, oi, dt));
  }
}

extern "C" void kernel_launch(void* const* d_in, const int* in_sizes, int n_in,
                              void* d_out, int out_size, void* d_ws, size_t ws_size,
                              hipStream_t stream) {
  (void)in_sizes; (void)n_in; (void)out_size;
  const void* q   = d_in[0];
  const void* seq = d_in[1];
  const void* rw  = d_in[2];
  const void* w1  = d_in[3];
  const void* w2  = d_in[4];
  const void* w3  = d_in[5];
  const void* wk  = d_in[6];
  const void* wv  = d_in[7];
  const int*  msk = (const int*)d_in[8];

  char* ws = (char*)d_ws;
  size_t off = 0;
  auto alloc = [&](size_t b) { void* p = ws + off; off = (off + b + 255) & ~(size_t)255; return p; };
  int*  flags = (int*)alloc(512);            // [0]=mflag, [2]=cnts0, [3]=cnts1, [4]=dflag
  int*  mflag = flags + 0;
  int*  cnts  = flags + 2;
  int*  dflag = flags + 4;
  u16t* Xn  = (u16t*)alloc((size_t)BT_ROWS * MODEL * 2);   // reused as H in-place per chunk
  u16t* W1t = (u16t*)alloc((size_t)FFNH * MODEL * 2);
  u16t* W2t = (u16t*)alloc((size_t)FFNH * MODEL * 2);
  u16t* W3t = (u16t*)alloc((size_t)MODEL * FFNH * 2);
  size_t actBytes = (ws_size > off) ? (ws_size - off) : 0;
  long tpc = (long)(actBytes / ((size_t)128 * FFNH * 2));
  if (tpc < 1) tpc = 1;
  if (tpc > 100) tpc = 100;   // 100 tiles -> 50 MB Act chunk, stays L3-resident gemm1->gemm2
  u16t* ActB = (u16t*)(ws + off);

  hipMemsetAsync(flags, 0, 512, stream);
  detect_dtype_k<<<dim3(1024), dim3(256), 0, stream>>>((const unsigned int*)w1, cnts);
  detect_finalize_k<<<dim3(1), dim3(64), 0, stream>>>(cnts, dflag);
  detect_mask_k<<<dim3(50), dim3(256), 0, stream>>>((const unsigned int*)msk, mflag);

  rmsnorm_k<<<dim3(BT_ROWS / 4), dim3(256), 0, stream>>>(seq, rw, dflag, Xn);
  transpose_k<<<dim3(FFNH / 32, MODEL / 32), dim3(256), 0, stream>>>(w1, W1t, dflag, MODEL, FFNH);
  transpose_k<<<dim3(FFNH / 32, MODEL / 32), dim3(256), 0, stream>>>(w2, W2t, dflag, MODEL, FFNH);
  transpose_k<<<dim3(MODEL / 32, FFNH / 32), dim3(256), 0, stream>>>(w3, W3t, dflag, FFNH, MODEL);

  for (int t0 = 0; t0 < 400; t0 += (int)tpc) {
    int tiles = (400 - t0 < (int)tpc) ? (400 - t0) : (int)tpc;
    int rows0 = t0 * 128;
    ffn_gemm1<<<dim3(FFNH / 64, tiles), dim3(256), 0, stream>>>(
        Xn + (size_t)rows0 * MODEL, W1t, W2t, ActB);
    ffn_gemm2<<<dim3(MODEL / 128, tiles), dim3(256), 0, stream>>>(
        ActB, W3t, seq, dflag, Xn, rows0);
  }
  attn_k<<<dim3(2048), dim3(256), 0, stream>>>(Xn, q, wk, wv, msk, mflag, dflag, d_out);
}

// Round 6
// 696.102 us; speedup vs baseline: 1.4469x; 1.1315x over previous
//
#include <hip/hip_runtime.h>
#include <hip/hip_fp16.h>
#include <cstdint>
#include <cstddef>

typedef unsigned short u16t;
typedef __bf16 bf16x8 __attribute__((ext_vector_type(8)));
typedef float f32x4 __attribute__((ext_vector_type(4)));
typedef unsigned short u16x8 __attribute__((ext_vector_type(8)));

#define BT_ROWS 51200   // B*T
#define MODEL 512
#define FFNH 2048

__device__ __forceinline__ float bf2f(u16t u) {
  union { unsigned int i; float f; } v; v.i = ((unsigned int)u) << 16; return v.f;
}
__device__ __forceinline__ u16t f2bf(float f) {
  union { float f; unsigned int i; } v; v.f = f;
  return (u16t)((v.i + 0x7fffu + ((v.i >> 16) & 1u)) >> 16);
}
// dt: 0 = bf16, 1 = fp32, 2 = fp16
__device__ __forceinline__ float ldf(const void* p, size_t i, int dt) {
  if (dt == 1) return ((const float*)p)[i];
  u16t u = ((const u16t*)p)[i];
  if (dt == 0) return bf2f(u);
  __half h; *(u16t*)&h = u; return __half2float(h);
}
__device__ __forceinline__ void stf(void* p, size_t i, int dt, float f) {
  if (dt == 1) { ((float*)p)[i] = f; }
  else if (dt == 0) { ((u16t*)p)[i] = f2bf(f); }
  else { __half h = __float2half(f); ((u16t*)p)[i] = *(u16t*)&h; }
}
__device__ __forceinline__ void gl2lds16(const void* g, void* l) {
  __builtin_amdgcn_global_load_lds((const __attribute__((address_space(1))) void*)g,
                                   (__attribute__((address_space(3))) void*)l, 16, 0, 0);
}

// ---------------- dtype probe on w1: ONE block, no atomics ----------------
// Samples 16384 words (64 KB). Xavier weights: |x| < 0.0485 in their own dtype.
__global__ __launch_bounds__(256) void detect_dtype_k(const unsigned int* __restrict__ w1,
                                                      int* __restrict__ dflag) {
  __shared__ int sh[8];
  int a = 0, bc = 0;
  for (int it = 0; it < 64; it++) {
    unsigned int w = w1[it * 256 + threadIdx.x];
    u16t lo = (u16t)(w & 0xffffu), hi = (u16t)(w >> 16);
    float flo = bf2f(lo);
    a += (!(fabsf(flo) < 0.25f)) ? 1 : 0;             // fires only for fp32 mantissa noise
    __half hh; *(u16t*)&hh = hi; float fhi = __half2float(hh);
    bc += (fabsf(fhi) > 0.25f && fabsf(fhi) < 256.f) ? 1 : 0;  // fires for bf16 bit patterns
  }
#pragma unroll
  for (int o = 32; o; o >>= 1) { a += __shfl_xor(a, o); bc += __shfl_xor(bc, o); }
  int w = threadIdx.x >> 6;
  if ((threadIdx.x & 63) == 0) { sh[w] = a; sh[4 + w] = bc; }
  __syncthreads();
  if (threadIdx.x == 0) {
    int A = sh[0] + sh[1] + sh[2] + sh[3];
    int B = sh[4] + sh[5] + sh[6] + sh[7];
    dflag[0] = (A > 256) ? 1 : ((B < 256) ? 2 : 0);   // 1=fp32, 2=fp16, 0=bf16
  }
}

// ---------------- Mask layout probe: flag=1 if byte-packed (<=1 atomic/wave) ----------------
__global__ __launch_bounds__(256) void detect_mask_k(const unsigned int* __restrict__ msk,
                                                     int* __restrict__ flag) {
  int i = blockIdx.x * 256 + threadIdx.x;
  int bad = 0;
  if (i < 12800) bad = (msk[i] > 1u) ? 1 : 0;        // exactly 51200 bytes, safe for int8 & int32
  unsigned long long bl = __ballot(bad);
  if ((threadIdx.x & 63) == 0 && bl) atomicOr(flag, 1);
}

// ---------------- RMSNorm: one wave per row of 512, output bf16 ----------------
__global__ __launch_bounds__(256) void rmsnorm_k(const void* __restrict__ seq,
                                                 const void* __restrict__ w,
                                                 const int* __restrict__ dfp,
                                                 u16t* __restrict__ xn) {
  const int dt = dfp[0];
  int row = blockIdx.x * 4 + (threadIdx.x >> 6);
  int lane = threadIdx.x & 63;
  size_t base = (size_t)row * MODEL + lane * 8;
  float x[8]; float ss = 0.f;
  if (dt == 0) {
    u16x8 xv = *(const u16x8*)((const u16t*)seq + base);
#pragma unroll
    for (int j = 0; j < 8; j++) { x[j] = bf2f(xv[j]); ss += x[j] * x[j]; }
  } else if (dt == 1) {
    const f32x4* p = (const f32x4*)((const float*)seq + base);
    f32x4 va = p[0], vb = p[1];
#pragma unroll
    for (int j = 0; j < 4; j++) { x[j] = va[j]; x[4 + j] = vb[j]; }
#pragma unroll
    for (int j = 0; j < 8; j++) ss += x[j] * x[j];
  } else {
#pragma unroll
    for (int j = 0; j < 8; j++) { x[j] = ldf(seq, base + j, dt); ss += x[j] * x[j]; }
  }
#pragma unroll
  for (int o = 32; o; o >>= 1) ss += __shfl_xor(ss, o);
  float rstd = rsqrtf(ss * (1.f / 512.f) + 1.1920929e-07f);
  u16x8 ov;
#pragma unroll
  for (int j = 0; j < 8; j++) ov[j] = f2bf(x[j] * rstd * ldf(w, lane * 8 + j, dt));
  *(u16x8*)(xn + base) = ov;
}

// ---------------- Transpose (R x C) -> (C x R) with dtype conversion to bf16 ----------------
__global__ __launch_bounds__(256) void transpose_k(const void* __restrict__ src,
                                                   u16t* __restrict__ dst,
                                                   const int* __restrict__ dfp,
                                                   int R, int C) {
  const int dt = dfp[0];
  __shared__ u16t tile[32][33];
  int x = threadIdx.x & 31, y = threadIdx.x >> 5;
  int c0 = blockIdx.x * 32, r0 = blockIdx.y * 32;
#pragma unroll
  for (int i = 0; i < 32; i += 8)
    tile[y + i][x] = f2bf(ldf(src, (size_t)(r0 + y + i) * C + c0 + x, dt));
  __syncthreads();
#pragma unroll
  for (int i = 0; i < 32; i += 8) dst[(size_t)(c0 + y + i) * R + r0 + x] = tile[x][y + i];
}

// LDS K-group XOR swizzle: physical group = logical ^ (row & 7). 2-way banks (free)
// instead of 16-way. Staging permutes the SOURCE k-group so data lands swizzled.

// ---------------- GEMM1: Act = silu(Xn@w1) * (Xn@w2), BM=128 BN=64 BK=64 ----------------
__global__ __launch_bounds__(256, 4) void ffn_gemm1(const u16t* __restrict__ Xn,
                                                    const u16t* __restrict__ W1t,
                                                    const u16t* __restrict__ W2t,
                                                    u16t* __restrict__ Act) {
  __shared__ u16t As[128 * 64];
  __shared__ u16t B1s[64 * 64];
  __shared__ u16t B2s[64 * 64];
  const int tid = threadIdx.x;
  const int lane = tid & 63;
  const int wave = tid >> 6;
  const int wr = wave >> 1, wc = wave & 1;
  const int quad = lane >> 4, l16 = lane & 15;
  const int nBase = blockIdx.x * 64;    // N-fastest for A-tile L2 locality
  const int mBase = blockIdx.y * 128;
  const int wuBase = tid & ~63;

  f32x4 acc1[4][2], acc2[4][2];
  const f32x4 zf = {0.f, 0.f, 0.f, 0.f};
#pragma unroll
  for (int i = 0; i < 4; i++)
#pragma unroll
    for (int j = 0; j < 2; j++) { acc1[i][j] = zf; acc2[i][j] = zf; }

  for (int kt = 0; kt < MODEL; kt += 64) {
#pragma unroll
    for (int c = 0; c < 4; c++) {
      int chunk = c * 256 + tid;
      int r = chunk >> 3, k8 = (chunk & 7) ^ (r & 7);   // swizzled source k-group
      gl2lds16(Xn + (size_t)(mBase + r) * MODEL + kt + k8 * 8, As + (size_t)(c * 256 + wuBase) * 8);
    }
#pragma unroll
    for (int c = 0; c < 2; c++) {
      int chunk = c * 256 + tid;
      int r = chunk >> 3, k8 = (chunk & 7) ^ (r & 7);
      gl2lds16(W1t + (size_t)(nBase + r) * MODEL + kt + k8 * 8, B1s + (size_t)(c * 256 + wuBase) * 8);
      gl2lds16(W2t + (size_t)(nBase + r) * MODEL + kt + k8 * 8, B2s + (size_t)(c * 256 + wuBase) * 8);
    }
    __syncthreads();
#pragma unroll
    for (int ks = 0; ks < 64; ks += 32) {
      bf16x8 a[4], b1[2], b2[2];
      const int sw = (ks >> 3) + quad;   // logical k-group
#pragma unroll
      for (int mi = 0; mi < 4; mi++) {
        int row = wr * 64 + mi * 16 + l16;
        a[mi] = *(const bf16x8*)(As + row * 64 + ((sw ^ (row & 7)) << 3));
      }
#pragma unroll
      for (int ni = 0; ni < 2; ni++) {
        int row = wc * 32 + ni * 16 + l16;
        b1[ni] = *(const bf16x8*)(B1s + row * 64 + ((sw ^ (row & 7)) << 3));
        b2[ni] = *(const bf16x8*)(B2s + row * 64 + ((sw ^ (row & 7)) << 3));
      }
#pragma unroll
      for (int mi = 0; mi < 4; mi++)
#pragma unroll
        for (int ni = 0; ni < 2; ni++) {
          acc1[mi][ni] = __builtin_amdgcn_mfma_f32_16x16x32_bf16(a[mi], b1[ni], acc1[mi][ni], 0, 0, 0);
          acc2[mi][ni] = __builtin_amdgcn_mfma_f32_16x16x32_bf16(a[mi], b2[ni], acc2[mi][ni], 0, 0, 0);
        }
    }
    __syncthreads();
  }
#pragma unroll
  for (int mi = 0; mi < 4; mi++)
#pragma unroll
    for (int ni = 0; ni < 2; ni++)
#pragma unroll
      for (int r = 0; r < 4; r++) {
        int row = mBase + wr * 64 + mi * 16 + quad * 4 + r;
        int col = nBase + wc * 32 + ni * 16 + l16;
        float g1 = acc1[mi][ni][r], g2 = acc2[mi][ni][r];
        float sl = g1 / (1.f + __expf(-g1));
        Act[(size_t)row * FFNH + col] = f2bf(sl * g2);
      }
}

// ---------------- GEMM2: H = Act@w3 + seq, BM=128 BN=128 BK=64 ----------------
__global__ __launch_bounds__(256, 4) void ffn_gemm2(const u16t* __restrict__ Act,
                                                    const u16t* __restrict__ W3t,
                                                    const void* __restrict__ Seq,
                                                    const int* __restrict__ dfp,
                                                    u16t* __restrict__ H, int rowOff) {
  __shared__ u16t As[128 * 64];
  __shared__ u16t Bs[128 * 64];
  const int dt = dfp[0];
  const int tid = threadIdx.x;
  const int lane = tid & 63;
  const int wave = tid >> 6;
  const int wr = wave >> 1, wc = wave & 1;
  const int quad = lane >> 4, l16 = lane & 15;
  const int nBase = blockIdx.x * 128;   // N-fastest
  const int mBase = blockIdx.y * 128;
  const int wuBase = tid & ~63;

  f32x4 acc[4][4];
  const f32x4 zf = {0.f, 0.f, 0.f, 0.f};
#pragma unroll
  for (int i = 0; i < 4; i++)
#pragma unroll
    for (int j = 0; j < 4; j++) acc[i][j] = zf;

  for (int kt = 0; kt < FFNH; kt += 64) {
#pragma unroll
    for (int c = 0; c < 4; c++) {
      int chunk = c * 256 + tid;
      int r = chunk >> 3, k8 = (chunk & 7) ^ (r & 7);
      gl2lds16(Act + (size_t)(mBase + r) * FFNH + kt + k8 * 8, As + (size_t)(c * 256 + wuBase) * 8);
      gl2lds16(W3t + (size_t)(nBase + r) * FFNH + kt + k8 * 8, Bs + (size_t)(c * 256 + wuBase) * 8);
    }
    __syncthreads();
#pragma unroll
    for (int ks = 0; ks < 64; ks += 32) {
      bf16x8 a[4], b[4];
      const int sw = (ks >> 3) + quad;
#pragma unroll
      for (int mi = 0; mi < 4; mi++) {
        int row = wr * 64 + mi * 16 + l16;
        a[mi] = *(const bf16x8*)(As + row * 64 + ((sw ^ (row & 7)) << 3));
      }
#pragma unroll
      for (int ni = 0; ni < 4; ni++) {
        int row = wc * 64 + ni * 16 + l16;
        b[ni] = *(const bf16x8*)(Bs + row * 64 + ((sw ^ (row & 7)) << 3));
      }
#pragma unroll
      for (int mi = 0; mi < 4; mi++)
#pragma unroll
        for (int ni = 0; ni < 4; ni++)
          acc[mi][ni] = __builtin_amdgcn_mfma_f32_16x16x32_bf16(a[mi], b[ni], acc[mi][ni], 0, 0, 0);
    }
    __syncthreads();
  }
#pragma unroll
  for (int mi = 0; mi < 4; mi++)
#pragma unroll
    for (int ni = 0; ni < 4; ni++)
#pragma unroll
      for (int r = 0; r < 4; r++) {
        int grow = rowOff + mBase + wr * 64 + mi * 16 + quad * 4 + r;
        int col = nBase + wc * 64 + ni * 16 + l16;
        float v = acc[mi][ni][r] + ldf(Seq, (size_t)grow * MODEL + col, dt);
        H[(size_t)grow * MODEL + col] = f2bf(v);
      }
}

// ---------------- Attention: one block per (b, head), data-parallel phases ----------------
// LDS row stride 66 u16 -> bank = (t + d/2) % 32 : 2-way in both read phases (free).
__global__ __launch_bounds__(256) void attn_k(const u16t* __restrict__ H,
                                              const void* __restrict__ q,
                                              const void* __restrict__ wk,
                                              const void* __restrict__ wv,
                                              const int* __restrict__ mask,
                                              const int* __restrict__ mflagp,
                                              const int* __restrict__ dfp,
                                              void* __restrict__ out) {
  const int b = blockIdx.x >> 3;
  const int n = blockIdx.x & 7;
  const int tid = threadIdx.x;
  const int w = tid >> 6;
  const int lane = tid & 63;
  const int T = 200;
  const int HS = 66;
  const int dt = dfp[0];
  const int mflag = mflagp[0];

  __shared__ u16t hbuf[200 * HS];   // 26.4 KB
  __shared__ float qk[64];
  __shared__ float sc[200];
  __shared__ float part[256];
  __shared__ float red[8];
  __shared__ float ctx[64];

  // ---- stage H slice: coalesced u16x8 global reads, scalar LDS writes ----
  for (int chunk = tid; chunk < 1600; chunk += 256) {
    int r = chunk >> 3, c = (chunk & 7) << 3;
    u16x8 v = *(const u16x8*)(H + (size_t)(b * 200 + r) * MODEL + n * 64 + c);
#pragma unroll
    for (int j = 0; j < 8; j++) hbuf[r * HS + c + j] = v[j];
  }

  // ---- qk[d] = sum_e wk[n][d][e] * q[b][n][e] ; 4 threads per output d ----
  {
    int d = tid >> 2, sub = tid & 3;
    float s = 0.f;
    size_t wb = ((size_t)n * 64 + d) * 64 + sub * 16;
    size_t qb = (size_t)(b * 8 + n) * 64 + sub * 16;
#pragma unroll
    for (int i = 0; i < 16; i++) s += ldf(wk, wb + i, dt) * ldf(q, qb + i, dt);
    part[tid] = s;
  }
  __syncthreads();
  if (tid < 64) qk[tid] = part[tid * 4] + part[tid * 4 + 1] + part[tid * 4 + 2] + part[tid * 4 + 3];
  __syncthreads();

  // ---- scores: thread t does 64 LDS FMAs (qk[] is broadcast) ----
  float sv = -INFINITY;
  if (tid < T) {
    float s = 0.f;
#pragma unroll 16
    for (int d = 0; d < 64; d++) s += bf2f(hbuf[tid * HS + d]) * qk[d];
    int mv = mflag ? (int)((const unsigned char*)mask)[b * 200 + tid] : mask[b * 200 + tid];
    sv = mv ? s * 0.125f : -INFINITY;
  }

  // ---- softmax over T ----
  float mx = sv;
#pragma unroll
  for (int o = 32; o; o >>= 1) mx = fmaxf(mx, __shfl_xor(mx, o));
  if (lane == 0) red[w] = mx;
  __syncthreads();
  float gmax = fmaxf(fmaxf(red[0], red[1]), fmaxf(red[2], red[3]));
  float e = 0.f;
  if (gmax == -INFINITY) {
    if (tid == 0) e = 1.f;              // NaN guard (reference guarantees mask[:,0]=True)
  } else if (tid < T) {
    e = __expf(sv - gmax);
  }
  float s = e;
#pragma unroll
  for (int o = 32; o; o >>= 1) s += __shfl_xor(s, o);
  if (lane == 0) red[4 + w] = s;
  __syncthreads();
  float inv = 1.f / (red[4] + red[5] + red[6] + red[7]);
  if (tid < T) sc[tid] = e * inv;
  __syncthreads();

  // ---- ctx[d] = sum_t p[t] * h[t][d] ; wave w covers t = w::4 ----
  float a2 = 0.f;
  for (int t = w; t < T; t += 4) a2 += sc[t] * bf2f(hbuf[t * HS + lane]);
  part[tid] = a2;
  __syncthreads();
  if (tid < 64) ctx[tid] = part[tid] + part[64 + tid] + part[128 + tid] + part[192 + tid];
  __syncthreads();

  // ---- out = ctx @ wv + q ; wave w covers d = w*16..w*16+15 ----
  {
    int od = tid & 63;
    float s2 = 0.f;
#pragma unroll
    for (int i = 0; i < 16; i++) {
      int d = w * 16 + i;
      s2 += ctx[d] * ldf(wv, ((size_t)n * 64 + d) * 64 + od, dt);
    }
    part[tid] = s2;
  }
  __syncthreads();
  if (tid < 64) {
    size_t oi = (size_t)(b * 8 + n) * 64 + tid;
    stf(out, oi, dt,
        part[tid] + part[64 + tid] + part[128 + tid] + part[192 + tid] + ldf(q, oi, dt));
  }
}

extern "C" void kernel_launch(void* const* d_in, const int* in_sizes, int n_in,
                              void* d_out, int out_size, void* d_ws, size_t ws_size,
                              hipStream_t stream) {
  (void)in_sizes; (void)n_in; (void)out_size;
  const void* q   = d_in[0];
  const void* seq = d_in[1];
  const void* rw  = d_in[2];
  const void* w1  = d_in[3];
  const void* w2  = d_in[4];
  const void* w3  = d_in[5];
  const void* wk  = d_in[6];
  const void* wv  = d_in[7];
  const int*  msk = (const int*)d_in[8];

  char* ws = (char*)d_ws;
  size_t off = 0;
  auto alloc = [&](size_t b) { void* p = ws + off; off = (off + b + 255) & ~(size_t)255; return p; };
  int*  flags = (int*)alloc(512);            // [0]=mflag, [4]=dflag
  int*  mflag = flags + 0;
  int*  dflag = flags + 4;
  u16t* Xn  = (u16t*)alloc((size_t)BT_ROWS * MODEL * 2);   // reused as H in-place per chunk
  u16t* W1t = (u16t*)alloc((size_t)FFNH * MODEL * 2);
  u16t* W2t = (u16t*)alloc((size_t)FFNH * MODEL * 2);
  u16t* W3t = (u16t*)alloc((size_t)MODEL * FFNH * 2);
  size_t actBytes = (ws_size > off) ? (ws_size - off) : 0;
  long tpc = (long)(actBytes / ((size_t)128 * FFNH * 2));
  if (tpc < 1) tpc = 1;
  if (tpc > 200) tpc = 200;   // 200 tiles -> 105 MB Act chunk, L3-resident gemm1->gemm2
  u16t* ActB = (u16t*)(ws + off);

  hipMemsetAsync(flags, 0, 512, stream);
  detect_dtype_k<<<dim3(1), dim3(256), 0, stream>>>((const unsigned int*)w1, dflag);
  detect_mask_k<<<dim3(50), dim3(256), 0, stream>>>((const unsigned int*)msk, mflag);

  rmsnorm_k<<<dim3(BT_ROWS / 4), dim3(256), 0, stream>>>(seq, rw, dflag, Xn);
  transpose_k<<<dim3(FFNH / 32, MODEL / 32), dim3(256), 0, stream>>>(w1, W1t, dflag, MODEL, FFNH);
  transpose_k<<<dim3(FFNH / 32, MODEL / 32), dim3(256), 0, stream>>>(w2, W2t, dflag, MODEL, FFNH);
  transpose_k<<<dim3(MODEL / 32, FFNH / 32), dim3(256), 0, stream>>>(w3, W3t, dflag, FFNH, MODEL);

  for (int t0 = 0; t0 < 400; t0 += (int)tpc) {
    int tiles = (400 - t0 < (int)tpc) ? (400 - t0) : (int)tpc;
    int rows0 = t0 * 128;
    ffn_gemm1<<<dim3(FFNH / 64, tiles), dim3(256), 0, stream>>>(
        Xn + (size_t)rows0 * MODEL, W1t, W2t, ActB);
    ffn_gemm2<<<dim3(MODEL / 128, tiles), dim3(256), 0, stream>>>(
        ActB, W3t, seq, dflag, Xn, rows0);
  }
  attn_k<<<dim3(2048), dim3(256), 0, stream>>>(Xn, q, wk, wv, msk, mflag, dflag, d_out);
}